// Round 18
// baseline (113.660 us; speedup 1.0000x reference)
//
#include <hip/hip_runtime.h>
#include <hip/hip_bf16.h>
#include <math.h>

#define NB 2
#define NL 2048
#define ND 1024
#define NH 16
#define NDH 64
#define NM (NB * NL)   // 4096 rows

typedef __bf16 bf16x8 __attribute__((ext_vector_type(8)));
typedef float  f32x4  __attribute__((ext_vector_type(4)));
typedef unsigned int   u32;
typedef unsigned short u16;

union FragU { u32 u[4]; bf16x8 v; };

__device__ __forceinline__ u32 f2bf(float f) {   // RTNE f32 -> bf16 bits
  u32 u = __float_as_uint(f);
  return (u + 0x7fffu + ((u >> 16) & 1u)) >> 16;
}
__device__ __forceinline__ float bf2f(u32 b) { return __uint_as_float(b << 16); }

// async global->LDS, 16B per lane; LDS dest wave-uniform base + lane*16
__device__ __forceinline__ void gload16(const void* g, void* l) {
  __builtin_amdgcn_global_load_lds(
      (const __attribute__((address_space(1))) u32*)g,
      (__attribute__((address_space(3))) u32*)l, 16, 0, 0);
}

// ===========================================================================
// Packed operand layout:
//   P[rb][kc][lane] : 16B chunk, rb = 16-row block, kc = 32-col(k) chunk
//   chunk(rb,kc,l) = { src[16rb+(l&15)][32kc+4(l>>4)+0..3],
//                      src[16rb+(l&15)][32kc+16+4(l>>4)+0..3] }  (bf16)
// ===========================================================================

// shared emit phase: Ls[16][1032] bf16 -> 32 kc * 64 lane chunks
__device__ __forceinline__ void pack_emit(const u16 Ls[16][1032],
                                          uint4* __restrict__ dst, int t) {
#pragma unroll
  for (int rep = 0; rep < 8; ++rep) {
    int c  = rep * 256 + t;          // 0..2047
    int kc = c >> 6, l = c & 63;
    int lo = l & 15, hi = l >> 4;
    int k0 = kc * 32 + hi * 4;
    uint4 o;
    o.x = (u32)Ls[lo][k0 + 0]  | ((u32)Ls[lo][k0 + 1]  << 16);
    o.y = (u32)Ls[lo][k0 + 2]  | ((u32)Ls[lo][k0 + 3]  << 16);
    o.z = (u32)Ls[lo][k0 + 16] | ((u32)Ls[lo][k0 + 17] << 16);
    o.w = (u32)Ls[lo][k0 + 18] | ((u32)Ls[lo][k0 + 19] << 16);
    dst[(size_t)kc * 64 + l] = o;
  }
}

// ---------------------------------------------------------------------------
// prep: one launch fusing three independent roles (block-uniform switch)
// ---------------------------------------------------------------------------
__global__ __launch_bounds__(256) void prep(
    const float* __restrict__ x,
    const float* __restrict__ Wq, const float* __restrict__ Wk,
    const float* __restrict__ Wv,
    uint4* __restrict__ PA,
    uint4* __restrict__ PWq, uint4* __restrict__ PWk, uint4* __restrict__ PWv,
    u32* __restrict__ tab) {
  __shared__ u16 Ls[16][1032];
  const int bid = blockIdx.x;
  const int t   = threadIdx.x;
  if (bid < 192) {
    const int wsel = bid >> 6;           // 0..2
    const int n16  = bid & 63;
    const float* W = (wsel == 0) ? Wq : (wsel == 1) ? Wk : Wv;
    uint4* P       = (wsel == 0) ? PWq : (wsel == 1) ? PWk : PWv;
    const int n0 = n16 * 16;
#pragma unroll
    for (int rep = 0; rep < 16; ++rep) {
      int k  = rep * 64 + (t >> 2);
      int c4 = (t & 3) * 4;
      float4 v = *(const float4*)(W + (size_t)k * ND + n0 + c4);
      Ls[c4 + 0][k] = (u16)f2bf(v.x); Ls[c4 + 1][k] = (u16)f2bf(v.y);
      Ls[c4 + 2][k] = (u16)f2bf(v.z); Ls[c4 + 3][k] = (u16)f2bf(v.w);
    }
    __syncthreads();
    pack_emit(Ls, P + (size_t)n16 * 32 * 64, t);
  } else if (bid < 448) {
    const int rb = bid - 192;
    const int row = t >> 4;
    const float* S = x + (size_t)(rb * 16 + row) * ND;
#pragma unroll
    for (int rep = 0; rep < 16; ++rep) {
      int c0 = (t & 15) * 4 + rep * 64;
      float4 v = *(const float4*)(S + c0);
      Ls[row][c0 + 0] = (u16)f2bf(v.x); Ls[row][c0 + 1] = (u16)f2bf(v.y);
      Ls[row][c0 + 2] = (u16)f2bf(v.z); Ls[row][c0 + 3] = (u16)f2bf(v.w);
    }
    __syncthreads();
    pack_emit(Ls, PA + (size_t)rb * 32 * 64, t);
  } else {
    int i = (bid - 448) * 256 + t;       // 0..65535
    int l = i >> 5, p = i & 31;
    float invf = expf(-(float)p * 0.28782313662425572f);   // ln(10000)/32
    float ang = (float)l * invf;
    float sn, cs;
    sincosf(ang, &sn, &cs);
    tab[i] = f2bf(cs) | (f2bf(sn) << 16);
  }
}

// pack W (Wo) as W^T fragments (runs after gemm_qkv_pack; dest reuses PWq)
__global__ __launch_bounds__(256) void pack_w(const float* __restrict__ W0,
                                              uint4* __restrict__ P0) {
  __shared__ u16 Ls[16][1032];
  const int n16 = blockIdx.x;
  const int t   = threadIdx.x;
  const int n0  = n16 * 16;
#pragma unroll
  for (int rep = 0; rep < 16; ++rep) {
    int k  = rep * 64 + (t >> 2);
    int c4 = (t & 3) * 4;
    float4 v = *(const float4*)(W0 + (size_t)k * ND + n0 + c4);
    Ls[c4 + 0][k] = (u16)f2bf(v.x); Ls[c4 + 1][k] = (u16)f2bf(v.y);
    Ls[c4 + 2][k] = (u16)f2bf(v.z); Ls[c4 + 3][k] = (u16)f2bf(v.w);
  }
  __syncthreads();
  pack_emit(Ls, P0 + (size_t)n16 * 32 * 64, t);
}

// ===========================================================================
// FUSED QKV GEMM v2: 64x128 tile (gemm_out-proven structure), grid (8,64,3)
// = 6 blocks/CU -> barrier drains overlap across co-resident blocks.
// 4 waves; wave w stages 3 chunks and owns cols [w*32, w*32+32); acc 4x2.
// Epilogue (per 64x128 tile): z=0/1 RoPE+pack PQ/PK (4 chunks/thread);
// z=2 transpose-pack PVp (tile = one 64-seq kt, 4 chunks/thread).
// ===========================================================================
__global__ __launch_bounds__(256) void gemm_qkv_pack(
    const uint4* __restrict__ PA,
    const uint4* __restrict__ PWq,
    const uint4* __restrict__ PWk,
    const uint4* __restrict__ PWv,
    uint4* __restrict__ PQ,
    uint4* __restrict__ PK,
    uint4* __restrict__ PVp,
    const u32* __restrict__ tab) {
  __shared__ __align__(16) u16 Es[64][136];    // 17408 B
  uint4* As = (uint4*)&Es[0][0];               // 4KB: 4 rb x 64 lanes
  uint4* Bs = As + 256;                        // 8KB: 8 cb x 64 lanes

  const int z  = blockIdx.z;
  const uint4* PB = (z == 0) ? PWq : (z == 1) ? PWk : PWv;
  const float scale = (z == 0) ? 0.03125f * 1.44269504f : 1.f;  // q*log2e
  int bx, by;
  {
    int fid = blockIdx.x + 8 * blockIdx.y;   // 0..511
    int sw  = (fid & 7) * 64 + (fid >> 3);   // bijective XCD swizzle
    bx = sw & 7;                             // 0..7
    by = sw >> 3;                            // 0..63
  }
  const int t  = threadIdx.x;
  const int w  = t >> 6, l = t & 63;
  const int lo = l & 15, hi = l >> 4;
  const int hi4 = hi * 4;

  // this wave's 3 staging chunks (c<4 -> A rb=c; c>=4 -> B cb=c-4)
  const uint4* gsrc[3];
  uint4* ldst[3];
#pragma unroll
  for (int r = 0; r < 3; ++r) {
    int c = 3 * w + r;
    if (c < 4) {
      gsrc[r] = PA + ((size_t)(by * 4 + c) * 32) * 64 + l;
      ldst[r] = As + c * 64;
    } else {
      gsrc[r] = PB + ((size_t)(bx * 8 + (c - 4)) * 32) * 64 + l;
      ldst[r] = Bs + (c - 4) * 64;
    }
  }

  f32x4 acc[4][2];
#pragma unroll
  for (int i = 0; i < 4; ++i)
#pragma unroll
    for (int j = 0; j < 2; ++j) acc[i][j] = (f32x4){0.f, 0.f, 0.f, 0.f};

  for (int kc = 0; kc < 32; ++kc) {
    __syncthreads();
#pragma unroll
    for (int r = 0; r < 3; ++r) gload16(gsrc[r] + kc * 64, ldst[r]);
    __syncthreads();

    FragU a[4], b[2];
#pragma unroll
    for (int i = 0; i < 4; ++i) *(uint4*)a[i].u = As[i * 64 + l];
#pragma unroll
    for (int j = 0; j < 2; ++j) *(uint4*)b[j].u = Bs[(w * 2 + j) * 64 + l];
#pragma unroll
    for (int i = 0; i < 4; ++i)
#pragma unroll
      for (int j = 0; j < 2; ++j)
        acc[i][j] = __builtin_amdgcn_mfma_f32_16x16x32_bf16(a[i].v, b[j].v,
                                                            acc[i][j], 0, 0, 0);
  }

  // ---- stage bf16 tile to Es: row = i*16 + hi4+reg, col = w*32 + j*16 + lo
  __syncthreads();   // all waves done reading As/Bs
#pragma unroll
  for (int i = 0; i < 4; ++i)
#pragma unroll
    for (int reg = 0; reg < 4; ++reg)
#pragma unroll
      for (int j = 0; j < 2; ++j)
        Es[i * 16 + hi4 + reg][w * 32 + j * 16 + lo] =
            (u16)f2bf(acc[i][j][reg] * scale);
  __syncthreads();

  if (z < 2) {
    // ---- Q/K: RoPE + packed emit (4 chunks per thread)
    uint4* dst = z ? PK : PQ;
#pragma unroll
    for (int rep = 0; rep < 4; ++rep) {
      int idx  = rep * 256 + t;          // 0..1023
      int rb_l = idx >> 8;               // 0..3
      int kc_l = (idx >> 6) & 3;         // 0..3
      int l2   = idx & 63;
      int lo2 = l2 & 15, hi2 = l2 >> 4;
      int rowl = rb_l * 16 + lo2;        // 0..63
      int c0   = kc_l * 32 + hi2 * 4;    // 0..124
      int lpos = (by * 64 + rowl) & (NL - 1);
      int d0   = bx * 128 + c0;
      int p0   = (d0 & 63) >> 1;         // pair index within head
      const u32* tp = tab + lpos * 32;
      u32 tt[4] = {tp[p0], tp[p0 + 1], tp[p0 + 8], tp[p0 + 9]};
      u16 e[8] = {Es[rowl][c0 + 0],  Es[rowl][c0 + 1],
                  Es[rowl][c0 + 2],  Es[rowl][c0 + 3],
                  Es[rowl][c0 + 16], Es[rowl][c0 + 17],
                  Es[rowl][c0 + 18], Es[rowl][c0 + 19]};
      u32 oo[4];
#pragma unroll
      for (int jj = 0; jj < 4; ++jj) {
        float c = bf2f(tt[jj] & 0xffffu), s2 = bf2f(tt[jj] >> 16);
        float x0 = bf2f(e[2 * jj]), x1 = bf2f(e[2 * jj + 1]);
        oo[jj] = f2bf(x0 * c - x1 * s2) | (f2bf(x1 * c + x0 * s2) << 16);
      }
      dst[(size_t)(by * 4 + rb_l) * 2048 + (bx * 4 + kc_l) * 64 + l2] =
          make_uint4(oo[0], oo[1], oo[2], oo[3]);
    }
  } else {
    // ---- V: transpose-pack to PVp (4 chunks per thread; tile = one kt)
    const int b  = by >> 5;              // batch
    const int kt = by & 31;              // 64-seq tile
#pragma unroll
    for (int rep = 0; rep < 4; ++rep) {
      int idx  = rep * 256 + t;          // 0..1023
      int hloc = idx >> 9;               // 0..1
      int dd   = (idx >> 7) & 3;         // 0..3
      int c32  = (idx >> 6) & 1;         // 0..1
      int l2   = idx & 63;
      int lo2 = l2 & 15, hi2 = l2 >> 4;
      int col = hloc * 64 + dd * 16 + lo2;
      int sb  = c32 * 32 + hi2 * 4;      // seq row base within tile
      uint4 o;
      o.x = (u32)Es[sb + 0][col]  | ((u32)Es[sb + 1][col]  << 16);
      o.y = (u32)Es[sb + 2][col]  | ((u32)Es[sb + 3][col]  << 16);
      o.z = (u32)Es[sb + 16][col] | ((u32)Es[sb + 17][col] << 16);
      o.w = (u32)Es[sb + 18][col] | ((u32)Es[sb + 19][col] << 16);
      int h  = bx * 2 + hloc;
      int bh = b * 16 + h;
      PVp[(((size_t)bh * 4 + dd) * 64 + kt * 2 + c32) * 64 + l2] = o;
    }
  }
}

// ===========================================================================
// Output-projection GEMM, 64x128 tile, grid (8,64) = 2 blocks/CU (R17 win).
// ===========================================================================
__global__ __launch_bounds__(256) void gemm_out(const uint4* __restrict__ PA,
                                                const uint4* __restrict__ PB,
                                                float* __restrict__ C) {
  __shared__ uint4 As[256];   // 4 rb x 64 lanes (4KB)
  __shared__ uint4 Bs[512];   // 8 cb x 64 lanes (8KB)
  int bx, by;
  {
    int fid = blockIdx.x + 8 * blockIdx.y;   // 0..511
    int sw  = (fid & 7) * 64 + (fid >> 3);
    bx = sw & 7;
    by = sw >> 3;
  }
  const int t  = threadIdx.x;
  const int w  = t >> 6, l = t & 63;
  const int lo = l & 15, hi = l >> 4;
  const int hi4 = hi * 4;

  const uint4* gsrc[3];
  uint4* ldst[3];
#pragma unroll
  for (int r = 0; r < 3; ++r) {
    int c = 3 * w + r;
    if (c < 4) {
      gsrc[r] = PA + ((size_t)(by * 4 + c) * 32) * 64 + l;
      ldst[r] = As + c * 64;
    } else {
      gsrc[r] = PB + ((size_t)(bx * 8 + (c - 4)) * 32) * 64 + l;
      ldst[r] = Bs + (c - 4) * 64;
    }
  }

  f32x4 acc[4][2];
#pragma unroll
  for (int i = 0; i < 4; ++i)
#pragma unroll
    for (int j = 0; j < 2; ++j) acc[i][j] = (f32x4){0.f, 0.f, 0.f, 0.f};

  for (int kc = 0; kc < 32; ++kc) {
    __syncthreads();
#pragma unroll
    for (int r = 0; r < 3; ++r) gload16(gsrc[r] + kc * 64, ldst[r]);
    __syncthreads();

    FragU a[4], b[2];
#pragma unroll
    for (int i = 0; i < 4; ++i) *(uint4*)a[i].u = As[i * 64 + l];
#pragma unroll
    for (int j = 0; j < 2; ++j) *(uint4*)b[j].u = Bs[(w * 2 + j) * 64 + l];
#pragma unroll
    for (int i = 0; i < 4; ++i)
#pragma unroll
      for (int j = 0; j < 2; ++j)
        acc[i][j] = __builtin_amdgcn_mfma_f32_16x16x32_bf16(a[i].v, b[j].v,
                                                            acc[i][j], 0, 0, 0);
  }

  const int row0 = by * 64 + hi4;
  const int col0 = bx * 128 + w * 32 + lo;
#pragma unroll
  for (int i = 0; i < 4; ++i)
#pragma unroll
    for (int reg = 0; reg < 4; ++reg) {
      const size_t rbase = (size_t)(row0 + i * 16 + reg) * ND + col0;
#pragma unroll
      for (int j = 0; j < 2; ++j) C[rbase + j * 16] = acc[i][j][reg];
    }
}

// ---------------------------------------------------------------------------
// Causal flash attention v10 (proven ~48us; structure floored across 7
// probes — K-prefetch spills, TLP/traffic/shuffle changes all neutral).
// ---------------------------------------------------------------------------
__global__ __launch_bounds__(64, 4) void attn_mfma10(
    const uint4* __restrict__ PQ,
    const uint4* __restrict__ PK,
    const uint4* __restrict__ PVp,
    u16* __restrict__ Yp0,
    u16* __restrict__ Yp1,
    float2* __restrict__ ML) {
  const int id = blockIdx.x;           // 0..4095
  const int bh = id & 31;
  const int half = (id >> 5) & 1;
  const int qg = 63 - (id >> 6);       // 32-row band, heavy first
  const int b = bh >> 4, h = bh & 15;
  const int l = threadIdx.x;           // 0..63
  const int lo = l & 15, hi = l >> 4;
  const int hi4 = hi * 4;

  const int nkt = (qg >> 1) + 1;       // total KV tiles for this band
  const int mid = (nkt + 1) >> 1;
  const int k0 = half ? mid : 0;
  const int k1 = half ? nkt : mid;

  FragU qf[2][2];
#pragma unroll
  for (int g = 0; g < 2; ++g) {
    const size_t rb = (size_t)b * 128 + qg * 2 + g;
#pragma unroll
    for (int c32 = 0; c32 < 2; ++c32)
      *(uint4*)qf[g][c32].u = PQ[(rb * 32 + 2 * h + c32) * 64 + l];
  }

  const uint4* kfb = PK + (((size_t)b * 128) * 32 + 2 * h) * 64 + l;
  const uint4* vfb = PVp + ((size_t)bh * 256) * 64 + l;

  float m_run[2] = {-1e30f, -1e30f};
  float l_run[2] = {0.f, 0.f};         // per-lane partial (16 keys each)
  f32x4 y[2][4];
#pragma unroll
  for (int g = 0; g < 2; ++g)
#pragma unroll
    for (int et = 0; et < 4; ++et) y[g][et] = (f32x4){0.f, 0.f, 0.f, 0.f};

  for (int kt = k0; kt < k1; ++kt) {
    FragU kf[8];
#pragma unroll
    for (int kg = 0; kg < 4; ++kg)
#pragma unroll
      for (int c32 = 0; c32 < 2; ++c32)
        *(uint4*)kf[kg * 2 + c32].u =
            kfb[((size_t)(kt * 4 + kg) * 32 + c32) * 64];

    f32x4 s[2][4];
    __builtin_amdgcn_s_setprio(1);
#pragma unroll
    for (int kg = 0; kg < 4; ++kg)
#pragma unroll
      for (int g = 0; g < 2; ++g) {
        f32x4 acc = (f32x4){0.f, 0.f, 0.f, 0.f};
        acc = __builtin_amdgcn_mfma_f32_16x16x32_bf16(kf[kg * 2 + 0].v,
                                                      qf[g][0].v, acc, 0, 0, 0);
        acc = __builtin_amdgcn_mfma_f32_16x16x32_bf16(kf[kg * 2 + 1].v,
                                                      qf[g][1].v, acc, 0, 0, 0);
        s[g][kg] = acc;
      }
    __builtin_amdgcn_s_setprio(0);

    FragU vf[8];
#pragma unroll
    for (int et = 0; et < 4; ++et)
#pragma unroll
      for (int c32 = 0; c32 < 2; ++c32)
        *(uint4*)vf[et * 2 + c32].u =
            vfb[(size_t)(et * 64 + kt * 2 + c32) * 64];

    if (kt == nkt - 1) {
#pragma unroll
      for (int g = 0; g < 2; ++g) {
        const int rowg = qg * 32 + g * 16 + lo;
#pragma unroll
        for (int kg = 0; kg < 4; ++kg)
#pragma unroll
          for (int reg = 0; reg < 4; ++reg)
            if (kt * 64 + kg * 16 + hi4 + reg > rowg) s[g][kg][reg] = -1e30f;
      }
    }

    FragU pa[2][2];
#pragma unroll
    for (int g = 0; g < 2; ++g) {
      float mt = s[g][0][0];
#pragma unroll
      for (int kg = 0; kg < 4; ++kg)
#pragma unroll
        for (int reg = 0; reg < 4; ++reg) mt = fmaxf(mt, s[g][kg][reg]);
      if (__any(mt > m_run[g] + 8.f)) {
        mt = fmaxf(mt, __shfl_xor(mt, 16));
        mt = fmaxf(mt, __shfl_xor(mt, 32));
        const float mnew = fmaxf(m_run[g], mt);
        const float corr = exp2f(m_run[g] - mnew);
        m_run[g] = mnew;
        l_run[g] *= corr;
        const float c0 = __shfl(corr, hi4 + 0);
        const float c1 = __shfl(corr, hi4 + 1);
        const float c2 = __shfl(corr, hi4 + 2);
        const float c3 = __shfl(corr, hi4 + 3);
#pragma unroll
        for (int et = 0; et < 4; ++et) {
          y[g][et][0] *= c0; y[g][et][1] *= c1;
          y[g][et][2] *= c2; y[g][et][3] *= c3;
        }
      }
      float ps = 0.f;
#pragma unroll
      for (int kg = 0; kg < 4; ++kg)
#pragma unroll
        for (int reg = 0; reg < 4; ++reg) {
          float e = exp2f(s[g][kg][reg] - m_run[g]);
          s[g][kg][reg] = e;
          ps += e;
        }
      l_run[g] += ps;

#pragma unroll
      for (int kg = 0; kg < 2; ++kg)
#pragma unroll
        for (int reg = 0; reg < 4; ++reg) {
          pa[g][0].v[kg * 4 + reg] = (__bf16)s[g][kg][reg];
          pa[g][1].v[kg * 4 + reg] = (__bf16)s[g][kg + 2][reg];
        }
    }

    __builtin_amdgcn_s_setprio(1);
#pragma unroll
    for (int et = 0; et < 4; ++et)
#pragma unroll
      for (int g = 0; g < 2; ++g) {
        y[g][et] = __builtin_amdgcn_mfma_f32_16x16x32_bf16(
            pa[g][0].v, vf[et * 2 + 0].v, y[g][et], 0, 0, 0);
        y[g][et] = __builtin_amdgcn_mfma_f32_16x16x32_bf16(
            pa[g][1].v, vf[et * 2 + 1].v, y[g][et], 0, 0, 0);
      }
    __builtin_amdgcn_s_setprio(0);
  }

  float lt[2];
#pragma unroll
  for (int g = 0; g < 2; ++g) {
    float v = l_run[g];
    v += __shfl_xor(v, 16);
    v += __shfl_xor(v, 32);
    lt[g] = v;
  }
  __bf16* Yb16 = (__bf16*)(half ? Yp1 : Yp0);
#pragma unroll
  for (int g = 0; g < 2; ++g) {
    const size_t ybase =
        (size_t)(b * NL + qg * 32 + g * 16) * ND + h * 64;
#pragma unroll
    for (int et = 0; et < 4; ++et) {
      Yb16[ybase + (size_t)(hi4 + 0) * ND + et * 16 + lo] = (__bf16)y[g][et][0];
      Yb16[ybase + (size_t)(hi4 + 1) * ND + et * 16 + lo] = (__bf16)y[g][et][1];
      Yb16[ybase + (size_t)(hi4 + 2) * ND + et * 16 + lo] = (__bf16)y[g][et][2];
      Yb16[ybase + (size_t)(hi4 + 3) * ND + et * 16 + lo] = (__bf16)y[g][et][3];
    }
  }
  if (l < 16) {
#pragma unroll
    for (int g = 0; g < 2; ++g) {
      const int unit = (b * NL + qg * 32 + g * 16 + l) * NH + h;
      ML[half * (NM * NH) + unit] = make_float2(m_run[g], lt[g]);
    }
  }
}

// ---------------------------------------------------------------------------
// combine_pack: merge the two split-K partials and emit packed PY fragments.
// ---------------------------------------------------------------------------
__global__ __launch_bounds__(256) void combine_pack(
    const u16* __restrict__ Yp0, const u16* __restrict__ Yp1,
    const float2* __restrict__ ML, uint4* __restrict__ dst) {
  __shared__ u16 Ls[16][1032];
  __shared__ float W0s[16][16];
  __shared__ float W1s[16][16];
  const int rb = blockIdx.x;
  const int t = threadIdx.x;
  {
    const int r16 = t >> 4, hh = t & 15;
    const int unit = (rb * 16 + r16) * NH + hh;
    const float2 a = ML[unit];
    const float2 c = ML[NM * NH + unit];
    const float m = fmaxf(a.x, c.x);
    const float w0 = exp2f(a.x - m);
    const float w1 = exp2f(c.x - m);
    const float linv = 1.f / (a.y * w0 + c.y * w1);
    W0s[r16][hh] = w0 * linv;
    W1s[r16][hh] = w1 * linv;
  }
  __syncthreads();
  const int row = t >> 4;
  const u16* S0 = Yp0 + (size_t)(rb * 16 + row) * ND;
  const u16* S1 = Yp1 + (size_t)(rb * 16 + row) * ND;
#pragma unroll
  for (int rep = 0; rep < 8; ++rep) {
    int c0 = (t & 15) * 8 + rep * 128;
    const float w0 = W0s[row][c0 >> 6];
    const float w1 = W1s[row][c0 >> 6];
    uint4 v0 = *(const uint4*)(S0 + c0);
    uint4 v1 = *(const uint4*)(S1 + c0);
    u32 a0[4] = {v0.x, v0.y, v0.z, v0.w};
    u32 a1[4] = {v1.x, v1.y, v1.z, v1.w};
#pragma unroll
    for (int jj = 0; jj < 4; ++jj) {
      float vlo = bf2f(a0[jj] & 0xffffu) * w0 + bf2f(a1[jj] & 0xffffu) * w1;
      float vhi = bf2f(a0[jj] >> 16) * w0 + bf2f(a1[jj] >> 16) * w1;
      Ls[row][c0 + 2 * jj]     = (u16)f2bf(vlo);
      Ls[row][c0 + 2 * jj + 1] = (u16)f2bf(vhi);
    }
  }
  __syncthreads();
  pack_emit(Ls, dst + (size_t)rb * 32 * 64, t);
}

// ---------------------------------------------------------------------------
extern "C" void kernel_launch(void* const* d_in, const int* in_sizes, int n_in,
                              void* d_out, int out_size, void* d_ws,
                              size_t ws_size, hipStream_t stream) {
  const float* x  = (const float*)d_in[0];
  const float* Wq = (const float*)d_in[1];
  const float* Wk = (const float*)d_in[2];
  const float* Wv = (const float*)d_in[3];
  const float* Wo = (const float*)d_in[4];
  float* out = (float*)d_out;

  // workspace layout (46.25 MB), 8MB regions with liveness-based reuse:
  //   R0 [0,8)   PQ  (gemm_qkv_pack->attn) -> PY (combine->gemm_out)
  //   R1 [8,16)  PK  (gemm_qkv_pack->attn)
  //   R2 [16,24) PVp (gemm_qkv_pack->attn)
  //   R3 [24,32) Yp0 (attn partial 0)
  //   R4 [32,40) PA  (prep->gemm_qkv_pack) -> Yp1 (attn partial 1)
  //   R5 [40,46) PWq|PWk|PWv (dead after gemm) -> PWo [40,42), ML [42,43)
  //   [46,46.25) rope tab
  char* ws = (char*)d_ws;
  uint4* PQ  = (uint4*)(ws);
  uint4* PY  = PQ;
  uint4* PK  = (uint4*)(ws + ((size_t)8 << 20));
  uint4* PVp = (uint4*)(ws + ((size_t)16 << 20));
  u16*   Yp0 = (u16*)(ws + ((size_t)24 << 20));
  uint4* PA  = (uint4*)(ws + ((size_t)32 << 20));
  u16*   Yp1 = (u16*)PA;
  uint4* PWq = (uint4*)(ws + ((size_t)40 << 20));
  uint4* PWk = (uint4*)(ws + ((size_t)42 << 20));
  uint4* PWv = (uint4*)(ws + ((size_t)44 << 20));
  uint4* PWo = PWq;
  float2* ML = (float2*)PWk;                   // 2 x 65536 x 8B = 1 MB
  u32*   tab = (u32*)(ws + ((size_t)46 << 20));

  dim3 blk(256);

  prep<<<dim3(704), blk, 0, stream>>>(x, Wq, Wk, Wv, PA, PWq, PWk, PWv, tab);
  gemm_qkv_pack<<<dim3(8, 64, 3), blk, 0, stream>>>(PA, PWq, PWk, PWv,
                                                    PQ, PK, PVp, tab);
  pack_w<<<dim3(64), blk, 0, stream>>>(Wo, PWo);
  attn_mfma10<<<dim3(64 * 32 * 2), dim3(64), 0, stream>>>(PQ, PK, PVp,
                                                          Yp0, Yp1, ML);
  combine_pack<<<dim3(NM / 16), blk, 0, stream>>>(Yp0, Yp1, ML, PY);
  gemm_out<<<dim3(8, 64), blk, 0, stream>>>(PY, PWo, out);
}

// Round 19
// 111.947 us; speedup vs baseline: 1.0153x; 1.0153x over previous
//
#include <hip/hip_runtime.h>
#include <hip/hip_bf16.h>
#include <math.h>

#define NB 2
#define NL 2048
#define ND 1024
#define NH 16
#define NDH 64
#define NM (NB * NL)   // 4096 rows

typedef __bf16 bf16x8 __attribute__((ext_vector_type(8)));
typedef float  f32x4  __attribute__((ext_vector_type(4)));
typedef unsigned int   u32;
typedef unsigned short u16;

union FragU { u32 u[4]; bf16x8 v; };

__device__ __forceinline__ u32 f2bf(float f) {   // RTNE f32 -> bf16 bits
  u32 u = __float_as_uint(f);
  return (u + 0x7fffu + ((u >> 16) & 1u)) >> 16;
}
__device__ __forceinline__ float bf2f(u32 b) { return __uint_as_float(b << 16); }

// async global->LDS, 16B per lane; LDS dest wave-uniform base + lane*16
__device__ __forceinline__ void gload16(const void* g, void* l) {
  __builtin_amdgcn_global_load_lds(
      (const __attribute__((address_space(1))) u32*)g,
      (__attribute__((address_space(3))) u32*)l, 16, 0, 0);
}

// XCD-aware bijective block swizzle for (8,32) grids
__device__ __forceinline__ void swz_block(int& bx, int& by) {
  int fid = blockIdx.x + 8 * blockIdx.y;   // 0..255
  int sw  = (fid & 7) * 32 + (fid >> 3);   // bijective
  bx = sw & 7;
  by = sw >> 3;
}

// ===========================================================================
// Packed operand layout:
//   P[rb][kc][lane] : 16B chunk, rb = 16-row block, kc = 32-col(k) chunk
//   chunk(rb,kc,l) = { src[16rb+(l&15)][32kc+4(l>>4)+0..3],
//                      src[16rb+(l&15)][32kc+16+4(l>>4)+0..3] }  (bf16)
// ===========================================================================

// shared emit phase: Ls[16][1032] bf16 -> 32 kc * 64 lane chunks
__device__ __forceinline__ void pack_emit(const u16 Ls[16][1032],
                                          uint4* __restrict__ dst, int t) {
#pragma unroll
  for (int rep = 0; rep < 8; ++rep) {
    int c  = rep * 256 + t;          // 0..2047
    int kc = c >> 6, l = c & 63;
    int lo = l & 15, hi = l >> 4;
    int k0 = kc * 32 + hi * 4;
    uint4 o;
    o.x = (u32)Ls[lo][k0 + 0]  | ((u32)Ls[lo][k0 + 1]  << 16);
    o.y = (u32)Ls[lo][k0 + 2]  | ((u32)Ls[lo][k0 + 3]  << 16);
    o.z = (u32)Ls[lo][k0 + 16] | ((u32)Ls[lo][k0 + 17] << 16);
    o.w = (u32)Ls[lo][k0 + 18] | ((u32)Ls[lo][k0 + 19] << 16);
    dst[(size_t)kc * 64 + l] = o;
  }
}

// ---------------------------------------------------------------------------
// prep: one launch fusing three independent roles (block-uniform switch)
// ---------------------------------------------------------------------------
__global__ __launch_bounds__(256) void prep(
    const float* __restrict__ x,
    const float* __restrict__ Wq, const float* __restrict__ Wk,
    const float* __restrict__ Wv,
    uint4* __restrict__ PA,
    uint4* __restrict__ PWq, uint4* __restrict__ PWk, uint4* __restrict__ PWv,
    u32* __restrict__ tab) {
  __shared__ u16 Ls[16][1032];
  const int bid = blockIdx.x;
  const int t   = threadIdx.x;
  if (bid < 192) {
    const int wsel = bid >> 6;           // 0..2
    const int n16  = bid & 63;
    const float* W = (wsel == 0) ? Wq : (wsel == 1) ? Wk : Wv;
    uint4* P       = (wsel == 0) ? PWq : (wsel == 1) ? PWk : PWv;
    const int n0 = n16 * 16;
#pragma unroll
    for (int rep = 0; rep < 16; ++rep) {
      int k  = rep * 64 + (t >> 2);
      int c4 = (t & 3) * 4;
      float4 v = *(const float4*)(W + (size_t)k * ND + n0 + c4);
      Ls[c4 + 0][k] = (u16)f2bf(v.x); Ls[c4 + 1][k] = (u16)f2bf(v.y);
      Ls[c4 + 2][k] = (u16)f2bf(v.z); Ls[c4 + 3][k] = (u16)f2bf(v.w);
    }
    __syncthreads();
    pack_emit(Ls, P + (size_t)n16 * 32 * 64, t);
  } else if (bid < 448) {
    const int rb = bid - 192;
    const int row = t >> 4;
    const float* S = x + (size_t)(rb * 16 + row) * ND;
#pragma unroll
    for (int rep = 0; rep < 16; ++rep) {
      int c0 = (t & 15) * 4 + rep * 64;
      float4 v = *(const float4*)(S + c0);
      Ls[row][c0 + 0] = (u16)f2bf(v.x); Ls[row][c0 + 1] = (u16)f2bf(v.y);
      Ls[row][c0 + 2] = (u16)f2bf(v.z); Ls[row][c0 + 3] = (u16)f2bf(v.w);
    }
    __syncthreads();
    pack_emit(Ls, PA + (size_t)rb * 32 * 64, t);
  } else {
    int i = (bid - 448) * 256 + t;       // 0..65535
    int l = i >> 5, p = i & 31;
    float invf = expf(-(float)p * 0.28782313662425572f);   // ln(10000)/32
    float ang = (float)l * invf;
    float sn, cs;
    sincosf(ang, &sn, &cs);
    tab[i] = f2bf(cs) | (f2bf(sn) << 16);
  }
}

// pack W (Wo) as W^T fragments (runs after gemm_qkv_pack; dest reuses PWq)
__global__ __launch_bounds__(256) void pack_w(const float* __restrict__ W0,
                                              uint4* __restrict__ P0) {
  __shared__ u16 Ls[16][1032];
  const int n16 = blockIdx.x;
  const int t   = threadIdx.x;
  const int n0  = n16 * 16;
#pragma unroll
  for (int rep = 0; rep < 16; ++rep) {
    int k  = rep * 64 + (t >> 2);
    int c4 = (t & 3) * 4;
    float4 v = *(const float4*)(W0 + (size_t)k * ND + n0 + c4);
    Ls[c4 + 0][k] = (u16)f2bf(v.x); Ls[c4 + 1][k] = (u16)f2bf(v.y);
    Ls[c4 + 2][k] = (u16)f2bf(v.z); Ls[c4 + 3][k] = (u16)f2bf(v.w);
  }
  __syncthreads();
  pack_emit(Ls, P0 + (size_t)n16 * 32 * 64, t);
}

// ===========================================================================
// FUSED QKV GEMM (R14/R17-proven: 128x128 tile, m97 structure BK=32,
// 2 barriers/K-step, global_load_lds staging, 3 blocks/CU) + XCD swizzle +
// fused epilogue: z=0/1 RoPE+pack PQ/PK; z=2 transpose-pack PVp.
// ===========================================================================
__global__ __launch_bounds__(256) void gemm_qkv_pack(
    const uint4* __restrict__ PA,
    const uint4* __restrict__ PWq,
    const uint4* __restrict__ PWk,
    const uint4* __restrict__ PWv,
    uint4* __restrict__ PQ,
    uint4* __restrict__ PK,
    uint4* __restrict__ PVp,
    const u32* __restrict__ tab) {
  __shared__ __align__(16) u16 Es[128][136];   // 34816 B
  uint4* As = (uint4*)&Es[0][0];
  uint4* Bs = As + 512;

  const int z  = blockIdx.z;
  const uint4* PB = (z == 0) ? PWq : (z == 1) ? PWk : PWv;
  const float scale = (z == 0) ? 0.03125f * 1.44269504f : 1.f;  // q*log2e
  int bx, by;
  swz_block(bx, by);
  const int t  = threadIdx.x;
  const int w  = t >> 6, l = t & 63;
  const int lo = l & 15, hi = l >> 4;
  const int wr = w >> 1, wc = w & 1;

  const uint4* pa0 = PA + ((size_t)(by * 8 + w * 2 + 0) * 32) * 64 + l;
  const uint4* pa1 = PA + ((size_t)(by * 8 + w * 2 + 1) * 32) * 64 + l;
  const uint4* pb0 = PB + ((size_t)(bx * 8 + w * 2 + 0) * 32) * 64 + l;
  const uint4* pb1 = PB + ((size_t)(bx * 8 + w * 2 + 1) * 32) * 64 + l;
  uint4* as0 = As + (w * 2 + 0) * 64;
  uint4* as1 = As + (w * 2 + 1) * 64;
  uint4* bs0 = Bs + (w * 2 + 0) * 64;
  uint4* bs1 = Bs + (w * 2 + 1) * 64;

  f32x4 acc[4][4];
#pragma unroll
  for (int i = 0; i < 4; ++i)
#pragma unroll
    for (int j = 0; j < 4; ++j) acc[i][j] = (f32x4){0.f, 0.f, 0.f, 0.f};

  for (int kc = 0; kc < 32; ++kc) {
    __syncthreads();                         // prior step's reads complete
    gload16(pa0 + kc * 64, as0);
    gload16(pa1 + kc * 64, as1);
    gload16(pb0 + kc * 64, bs0);
    gload16(pb1 + kc * 64, bs1);
    __syncthreads();                         // staging complete

    FragU a[4], b[4];
#pragma unroll
    for (int i = 0; i < 4; ++i) *(uint4*)a[i].u = As[(wr * 4 + i) * 64 + l];
#pragma unroll
    for (int j = 0; j < 4; ++j) *(uint4*)b[j].u = Bs[(wc * 4 + j) * 64 + l];
#pragma unroll
    for (int i = 0; i < 4; ++i)
#pragma unroll
      for (int j = 0; j < 4; ++j)
        acc[i][j] = __builtin_amdgcn_mfma_f32_16x16x32_bf16(a[i].v, b[j].v,
                                                            acc[i][j], 0, 0, 0);
  }

  // ---- stage bf16 tile to Es
  __syncthreads();   // all waves done reading As/Bs
  {
    const int r0 = wr * 64 + hi * 4;
    const int c0 = wc * 64 + lo;
#pragma unroll
    for (int i = 0; i < 4; ++i)
#pragma unroll
      for (int reg = 0; reg < 4; ++reg)
#pragma unroll
        for (int j = 0; j < 4; ++j)
          Es[r0 + i * 16 + reg][c0 + j * 16] =
              (u16)f2bf(acc[i][j][reg] * scale);
  }
  __syncthreads();

  if (z < 2) {
    // ---- Q/K: RoPE + packed emit (8 chunks per thread)
    uint4* dst = z ? PK : PQ;
#pragma unroll
    for (int rep = 0; rep < 8; ++rep) {
      int idx  = rep * 256 + t;          // 0..2047
      int rb_l = idx >> 8;               // 0..7
      int kc_l = (idx >> 6) & 3;         // 0..3
      int l2   = idx & 63;
      int lo2 = l2 & 15, hi2 = l2 >> 4;
      int rowl = rb_l * 16 + lo2;        // 0..127
      int c0   = kc_l * 32 + hi2 * 4;    // 0..124
      int lpos = (by * 128 + rowl) & (NL - 1);
      int d0   = bx * 128 + c0;
      int p0   = (d0 & 63) >> 1;         // pair index within head
      const u32* tp = tab + lpos * 32;
      u32 tt[4] = {tp[p0], tp[p0 + 1], tp[p0 + 8], tp[p0 + 9]};
      u16 e[8] = {Es[rowl][c0 + 0],  Es[rowl][c0 + 1],
                  Es[rowl][c0 + 2],  Es[rowl][c0 + 3],
                  Es[rowl][c0 + 16], Es[rowl][c0 + 17],
                  Es[rowl][c0 + 18], Es[rowl][c0 + 19]};
      u32 oo[4];
#pragma unroll
      for (int jj = 0; jj < 4; ++jj) {
        float c = bf2f(tt[jj] & 0xffffu), s2 = bf2f(tt[jj] >> 16);
        float x0 = bf2f(e[2 * jj]), x1 = bf2f(e[2 * jj + 1]);
        oo[jj] = f2bf(x0 * c - x1 * s2) | (f2bf(x1 * c + x0 * s2) << 16);
      }
      dst[(size_t)(by * 8 + rb_l) * 2048 + (bx * 4 + kc_l) * 64 + l2] =
          make_uint4(oo[0], oo[1], oo[2], oo[3]);
    }
  } else {
    // ---- V: transpose-pack to PVp (8 chunks per thread)
    const int b = by >> 4;
#pragma unroll
    for (int rep = 0; rep < 8; ++rep) {
      int idx  = rep * 256 + t;          // 0..2047
      int hloc = idx >> 10;              // 0..1
      int dd   = (idx >> 8) & 3;         // 0..3
      int ktl  = (idx >> 7) & 1;         // 0..1
      int c32  = (idx >> 6) & 1;
      int l2   = idx & 63;
      int lo2 = l2 & 15, hi2 = l2 >> 4;
      int col = hloc * 64 + dd * 16 + lo2;
      int sb  = ktl * 64 + c32 * 32 + hi2 * 4;
      uint4 o;
      o.x = (u32)Es[sb + 0][col]  | ((u32)Es[sb + 1][col]  << 16);
      o.y = (u32)Es[sb + 2][col]  | ((u32)Es[sb + 3][col]  << 16);
      o.z = (u32)Es[sb + 16][col] | ((u32)Es[sb + 17][col] << 16);
      o.w = (u32)Es[sb + 18][col] | ((u32)Es[sb + 19][col] << 16);
      int h  = bx * 2 + hloc;
      int bh = b * 16 + h;
      int kt = (by & 15) * 2 + ktl;
      PVp[(((size_t)bh * 4 + dd) * 64 + kt * 2 + c32) * 64 + l2] = o;
    }
  }
}

// ===========================================================================
// Output-projection GEMM, 64x128 tile, grid (8,64) = 2 blocks/CU (R17 win).
// ===========================================================================
__global__ __launch_bounds__(256) void gemm_out(const uint4* __restrict__ PA,
                                                const uint4* __restrict__ PB,
                                                float* __restrict__ C) {
  __shared__ uint4 As[256];   // 4 rb x 64 lanes (4KB)
  __shared__ uint4 Bs[512];   // 8 cb x 64 lanes (8KB)
  int bx, by;
  {
    int fid = blockIdx.x + 8 * blockIdx.y;   // 0..511
    int sw  = (fid & 7) * 64 + (fid >> 3);
    bx = sw & 7;
    by = sw >> 3;
  }
  const int t  = threadIdx.x;
  const int w  = t >> 6, l = t & 63;
  const int lo = l & 15, hi = l >> 4;
  const int hi4 = hi * 4;

  const uint4* gsrc[3];
  uint4* ldst[3];
#pragma unroll
  for (int r = 0; r < 3; ++r) {
    int c = 3 * w + r;
    if (c < 4) {
      gsrc[r] = PA + ((size_t)(by * 4 + c) * 32) * 64 + l;
      ldst[r] = As + c * 64;
    } else {
      gsrc[r] = PB + ((size_t)(bx * 8 + (c - 4)) * 32) * 64 + l;
      ldst[r] = Bs + (c - 4) * 64;
    }
  }

  f32x4 acc[4][2];
#pragma unroll
  for (int i = 0; i < 4; ++i)
#pragma unroll
    for (int j = 0; j < 2; ++j) acc[i][j] = (f32x4){0.f, 0.f, 0.f, 0.f};

  for (int kc = 0; kc < 32; ++kc) {
    __syncthreads();
#pragma unroll
    for (int r = 0; r < 3; ++r) gload16(gsrc[r] + kc * 64, ldst[r]);
    __syncthreads();

    FragU a[4], b[2];
#pragma unroll
    for (int i = 0; i < 4; ++i) *(uint4*)a[i].u = As[i * 64 + l];
#pragma unroll
    for (int j = 0; j < 2; ++j) *(uint4*)b[j].u = Bs[(w * 2 + j) * 64 + l];
#pragma unroll
    for (int i = 0; i < 4; ++i)
#pragma unroll
      for (int j = 0; j < 2; ++j)
        acc[i][j] = __builtin_amdgcn_mfma_f32_16x16x32_bf16(a[i].v, b[j].v,
                                                            acc[i][j], 0, 0, 0);
  }

  const int row0 = by * 64 + hi4;
  const int col0 = bx * 128 + w * 32 + lo;
#pragma unroll
  for (int i = 0; i < 4; ++i)
#pragma unroll
    for (int reg = 0; reg < 4; ++reg) {
      const size_t rbase = (size_t)(row0 + i * 16 + reg) * ND + col0;
#pragma unroll
      for (int j = 0; j < 2; ++j) C[rbase + j * 16] = acc[i][j][reg];
    }
}

// ---------------------------------------------------------------------------
// Causal flash attention v10 (proven ~48us; structure floored across 7
// probes — K-prefetch spills at this register budget, TLP/traffic/shuffle
// changes all neutral).
// ---------------------------------------------------------------------------
__global__ __launch_bounds__(64, 4) void attn_mfma10(
    const uint4* __restrict__ PQ,
    const uint4* __restrict__ PK,
    const uint4* __restrict__ PVp,
    u16* __restrict__ Yp0,
    u16* __restrict__ Yp1,
    float2* __restrict__ ML) {
  const int id = blockIdx.x;           // 0..4095
  const int bh = id & 31;
  const int half = (id >> 5) & 1;
  const int qg = 63 - (id >> 6);       // 32-row band, heavy first
  const int b = bh >> 4, h = bh & 15;
  const int l = threadIdx.x;           // 0..63
  const int lo = l & 15, hi = l >> 4;
  const int hi4 = hi * 4;

  const int nkt = (qg >> 1) + 1;       // total KV tiles for this band
  const int mid = (nkt + 1) >> 1;
  const int k0 = half ? mid : 0;
  const int k1 = half ? nkt : mid;

  FragU qf[2][2];
#pragma unroll
  for (int g = 0; g < 2; ++g) {
    const size_t rb = (size_t)b * 128 + qg * 2 + g;
#pragma unroll
    for (int c32 = 0; c32 < 2; ++c32)
      *(uint4*)qf[g][c32].u = PQ[(rb * 32 + 2 * h + c32) * 64 + l];
  }

  const uint4* kfb = PK + (((size_t)b * 128) * 32 + 2 * h) * 64 + l;
  const uint4* vfb = PVp + ((size_t)bh * 256) * 64 + l;

  float m_run[2] = {-1e30f, -1e30f};
  float l_run[2] = {0.f, 0.f};         // per-lane partial (16 keys each)
  f32x4 y[2][4];
#pragma unroll
  for (int g = 0; g < 2; ++g)
#pragma unroll
    for (int et = 0; et < 4; ++et) y[g][et] = (f32x4){0.f, 0.f, 0.f, 0.f};

  for (int kt = k0; kt < k1; ++kt) {
    FragU kf[8];
#pragma unroll
    for (int kg = 0; kg < 4; ++kg)
#pragma unroll
      for (int c32 = 0; c32 < 2; ++c32)
        *(uint4*)kf[kg * 2 + c32].u =
            kfb[((size_t)(kt * 4 + kg) * 32 + c32) * 64];

    f32x4 s[2][4];
    __builtin_amdgcn_s_setprio(1);
#pragma unroll
    for (int kg = 0; kg < 4; ++kg)
#pragma unroll
      for (int g = 0; g < 2; ++g) {
        f32x4 acc = (f32x4){0.f, 0.f, 0.f, 0.f};
        acc = __builtin_amdgcn_mfma_f32_16x16x32_bf16(kf[kg * 2 + 0].v,
                                                      qf[g][0].v, acc, 0, 0, 0);
        acc = __builtin_amdgcn_mfma_f32_16x16x32_bf16(kf[kg * 2 + 1].v,
                                                      qf[g][1].v, acc, 0, 0, 0);
        s[g][kg] = acc;
      }
    __builtin_amdgcn_s_setprio(0);

    FragU vf[8];
#pragma unroll
    for (int et = 0; et < 4; ++et)
#pragma unroll
      for (int c32 = 0; c32 < 2; ++c32)
        *(uint4*)vf[et * 2 + c32].u =
            vfb[(size_t)(et * 64 + kt * 2 + c32) * 64];

    if (kt == nkt - 1) {
#pragma unroll
      for (int g = 0; g < 2; ++g) {
        const int rowg = qg * 32 + g * 16 + lo;
#pragma unroll
        for (int kg = 0; kg < 4; ++kg)
#pragma unroll
          for (int reg = 0; reg < 4; ++reg)
            if (kt * 64 + kg * 16 + hi4 + reg > rowg) s[g][kg][reg] = -1e30f;
      }
    }

    FragU pa[2][2];
#pragma unroll
    for (int g = 0; g < 2; ++g) {
      float mt = s[g][0][0];
#pragma unroll
      for (int kg = 0; kg < 4; ++kg)
#pragma unroll
        for (int reg = 0; reg < 4; ++reg) mt = fmaxf(mt, s[g][kg][reg]);
      if (__any(mt > m_run[g] + 8.f)) {
        mt = fmaxf(mt, __shfl_xor(mt, 16));
        mt = fmaxf(mt, __shfl_xor(mt, 32));
        const float mnew = fmaxf(m_run[g], mt);
        const float corr = exp2f(m_run[g] - mnew);
        m_run[g] = mnew;
        l_run[g] *= corr;
        const float c0 = __shfl(corr, hi4 + 0);
        const float c1 = __shfl(corr, hi4 + 1);
        const float c2 = __shfl(corr, hi4 + 2);
        const float c3 = __shfl(corr, hi4 + 3);
#pragma unroll
        for (int et = 0; et < 4; ++et) {
          y[g][et][0] *= c0; y[g][et][1] *= c1;
          y[g][et][2] *= c2; y[g][et][3] *= c3;
        }
      }
      float ps = 0.f;
#pragma unroll
      for (int kg = 0; kg < 4; ++kg)
#pragma unroll
        for (int reg = 0; reg < 4; ++reg) {
          float e = exp2f(s[g][kg][reg] - m_run[g]);
          s[g][kg][reg] = e;
          ps += e;
        }
      l_run[g] += ps;

#pragma unroll
      for (int kg = 0; kg < 2; ++kg)
#pragma unroll
        for (int reg = 0; reg < 4; ++reg) {
          pa[g][0].v[kg * 4 + reg] = (__bf16)s[g][kg][reg];
          pa[g][1].v[kg * 4 + reg] = (__bf16)s[g][kg + 2][reg];
        }
    }

    __builtin_amdgcn_s_setprio(1);
#pragma unroll
    for (int et = 0; et < 4; ++et)
#pragma unroll
      for (int g = 0; g < 2; ++g) {
        y[g][et] = __builtin_amdgcn_mfma_f32_16x16x32_bf16(
            pa[g][0].v, vf[et * 2 + 0].v, y[g][et], 0, 0, 0);
        y[g][et] = __builtin_amdgcn_mfma_f32_16x16x32_bf16(
            pa[g][1].v, vf[et * 2 + 1].v, y[g][et], 0, 0, 0);
      }
    __builtin_amdgcn_s_setprio(0);
  }

  float lt[2];
#pragma unroll
  for (int g = 0; g < 2; ++g) {
    float v = l_run[g];
    v += __shfl_xor(v, 16);
    v += __shfl_xor(v, 32);
    lt[g] = v;
  }
  __bf16* Yb16 = (__bf16*)(half ? Yp1 : Yp0);
#pragma unroll
  for (int g = 0; g < 2; ++g) {
    const size_t ybase =
        (size_t)(b * NL + qg * 32 + g * 16) * ND + h * 64;
#pragma unroll
    for (int et = 0; et < 4; ++et) {
      Yb16[ybase + (size_t)(hi4 + 0) * ND + et * 16 + lo] = (__bf16)y[g][et][0];
      Yb16[ybase + (size_t)(hi4 + 1) * ND + et * 16 + lo] = (__bf16)y[g][et][1];
      Yb16[ybase + (size_t)(hi4 + 2) * ND + et * 16 + lo] = (__bf16)y[g][et][2];
      Yb16[ybase + (size_t)(hi4 + 3) * ND + et * 16 + lo] = (__bf16)y[g][et][3];
    }
  }
  if (l < 16) {
#pragma unroll
    for (int g = 0; g < 2; ++g) {
      const int unit = (b * NL + qg * 32 + g * 16 + l) * NH + h;
      ML[half * (NM * NH) + unit] = make_float2(m_run[g], lt[g]);
    }
  }
}

// ---------------------------------------------------------------------------
// combine_pack: merge the two split-K partials and emit packed PY fragments.
// ---------------------------------------------------------------------------
__global__ __launch_bounds__(256) void combine_pack(
    const u16* __restrict__ Yp0, const u16* __restrict__ Yp1,
    const float2* __restrict__ ML, uint4* __restrict__ dst) {
  __shared__ u16 Ls[16][1032];
  __shared__ float W0s[16][16];
  __shared__ float W1s[16][16];
  const int rb = blockIdx.x;
  const int t = threadIdx.x;
  {
    const int r16 = t >> 4, hh = t & 15;
    const int unit = (rb * 16 + r16) * NH + hh;
    const float2 a = ML[unit];
    const float2 c = ML[NM * NH + unit];
    const float m = fmaxf(a.x, c.x);
    const float w0 = exp2f(a.x - m);
    const float w1 = exp2f(c.x - m);
    const float linv = 1.f / (a.y * w0 + c.y * w1);
    W0s[r16][hh] = w0 * linv;
    W1s[r16][hh] = w1 * linv;
  }
  __syncthreads();
  const int row = t >> 4;
  const u16* S0 = Yp0 + (size_t)(rb * 16 + row) * ND;
  const u16* S1 = Yp1 + (size_t)(rb * 16 + row) * ND;
#pragma unroll
  for (int rep = 0; rep < 8; ++rep) {
    int c0 = (t & 15) * 8 + rep * 128;
    const float w0 = W0s[row][c0 >> 6];
    const float w1 = W1s[row][c0 >> 6];
    uint4 v0 = *(const uint4*)(S0 + c0);
    uint4 v1 = *(const uint4*)(S1 + c0);
    u32 a0[4] = {v0.x, v0.y, v0.z, v0.w};
    u32 a1[4] = {v1.x, v1.y, v1.z, v1.w};
#pragma unroll
    for (int jj = 0; jj < 4; ++jj) {
      float vlo = bf2f(a0[jj] & 0xffffu) * w0 + bf2f(a1[jj] & 0xffffu) * w1;
      float vhi = bf2f(a0[jj] >> 16) * w0 + bf2f(a1[jj] >> 16) * w1;
      Ls[row][c0 + 2 * jj]     = (u16)f2bf(vlo);
      Ls[row][c0 + 2 * jj + 1] = (u16)f2bf(vhi);
    }
  }
  __syncthreads();
  pack_emit(Ls, dst + (size_t)rb * 32 * 64, t);
}

// ---------------------------------------------------------------------------
extern "C" void kernel_launch(void* const* d_in, const int* in_sizes, int n_in,
                              void* d_out, int out_size, void* d_ws,
                              size_t ws_size, hipStream_t stream) {
  const float* x  = (const float*)d_in[0];
  const float* Wq = (const float*)d_in[1];
  const float* Wk = (const float*)d_in[2];
  const float* Wv = (const float*)d_in[3];
  const float* Wo = (const float*)d_in[4];
  float* out = (float*)d_out;

  // workspace layout (46.25 MB), 8MB regions with liveness-based reuse:
  //   R0 [0,8)   PQ  (gemm_qkv_pack->attn) -> PY (combine->gemm_out)
  //   R1 [8,16)  PK  (gemm_qkv_pack->attn)
  //   R2 [16,24) PVp (gemm_qkv_pack->attn)
  //   R3 [24,32) Yp0 (attn partial 0)
  //   R4 [32,40) PA  (prep->gemm_qkv_pack) -> Yp1 (attn partial 1)
  //   R5 [40,46) PWq|PWk|PWv (dead after gemm) -> PWo [40,42), ML [42,43)
  //   [46,46.25) rope tab
  char* ws = (char*)d_ws;
  uint4* PQ  = (uint4*)(ws);
  uint4* PY  = PQ;
  uint4* PK  = (uint4*)(ws + ((size_t)8 << 20));
  uint4* PVp = (uint4*)(ws + ((size_t)16 << 20));
  u16*   Yp0 = (u16*)(ws + ((size_t)24 << 20));
  uint4* PA  = (uint4*)(ws + ((size_t)32 << 20));
  u16*   Yp1 = (u16*)PA;
  uint4* PWq = (uint4*)(ws + ((size_t)40 << 20));
  uint4* PWk = (uint4*)(ws + ((size_t)42 << 20));
  uint4* PWv = (uint4*)(ws + ((size_t)44 << 20));
  uint4* PWo = PWq;
  float2* ML = (float2*)PWk;                   // 2 x 65536 x 8B = 1 MB
  u32*   tab = (u32*)(ws + ((size_t)46 << 20));

  dim3 blk(256);

  prep<<<dim3(704), blk, 0, stream>>>(x, Wq, Wk, Wv, PA, PWq, PWk, PWv, tab);
  gemm_qkv_pack<<<dim3(8, 32, 3), blk, 0, stream>>>(PA, PWq, PWk, PWv,
                                                    PQ, PK, PVp, tab);
  pack_w<<<dim3(64), blk, 0, stream>>>(Wo, PWo);
  attn_mfma10<<<dim3(64 * 32 * 2), dim3(64), 0, stream>>>(PQ, PK, PVp,
                                                          Yp0, Yp1, ML);
  combine_pack<<<dim3(NM / 16), blk, 0, stream>>>(Yp0, Yp1, ML, PY);
  gemm_out<<<dim3(8, 64), blk, 0, stream>>>(PY, PWo, out);
}